// Round 8
// baseline (341.354 us; speedup 1.0000x reference)
//
#include <hip/hip_runtime.h>

// Problem constants
#define Bsz 16
#define Nseq 784
#define DIM 512
#define NH 8
#define KD 64
#define VD 256
#define QKV_OUT 3072   // (2*64+256)*8
#define HV 2048        // NH*VD
#define NN 614656      // 784*784

typedef __attribute__((ext_vector_type(8))) short short8;
typedef __attribute__((ext_vector_type(4))) float floatx4;
typedef __attribute__((ext_vector_type(16))) float floatx16;

#define OSTR 136  // LDS row stride for qkv epilogue tile (bf16): 272B, 16B-aligned
#define LOG2E 1.44269504f

#if __has_builtin(__builtin_amdgcn_exp2f)
#define EXP2(x) __builtin_amdgcn_exp2f(x)
#else
#define EXP2(x) exp2f(x)
#endif

__device__ __forceinline__ unsigned short f2bf(float f) {
  union { float f; unsigned u; } v; v.f = f;
  unsigned r = v.u + 0x7fffu + ((v.u >> 16) & 1u);
  return (unsigned short)(r >> 16);
}
__device__ __forceinline__ float bf2f(unsigned short u) {
  union { unsigned u; float f; } v; v.u = ((unsigned)u) << 16;
  return v.f;
}

// async global->LDS, 16B per lane; LDS dst = wave-uniform base + lane*16
__device__ __forceinline__ void glds16(const unsigned short* g, unsigned short* l) {
  __builtin_amdgcn_global_load_lds(
      (const __attribute__((address_space(1))) void*)g,
      (__attribute__((address_space(3))) void*)l, 16, 0, 0);
}

// ---------------- K0: fused fp32 -> bf16 convert (x, qkv_w, proj_w) ----------------
#define N4X 1605632   // x float4s
#define N4Q 393216    // qkv_w float4s
#define N4P 262144    // proj_w float4s
__global__ void cvt_all_kernel(const float* __restrict__ x,
                               const float* __restrict__ qw,
                               const float* __restrict__ pw,
                               unsigned short* __restrict__ xb,
                               unsigned short* __restrict__ wq,
                               unsigned short* __restrict__ wp) {
  int i = blockIdx.x * 256 + threadIdx.x;
  const float4* s; ushort4* d; int off;
  if (i < N4X)              { s = (const float4*)x;  d = (ushort4*)xb; off = i; }
  else if (i < N4X + N4Q)   { s = (const float4*)qw; d = (ushort4*)wq; off = i - N4X; }
  else if (i < N4X + N4Q + N4P) { s = (const float4*)pw; d = (ushort4*)wp; off = i - N4X - N4Q; }
  else return;
  float4 v = s[off];
  ushort4 o;
  o.x = f2bf(v.x); o.y = f2bf(v.y); o.z = f2bf(v.z); o.w = f2bf(v.w);
  d[off] = o;
}

// ---------------- K0b: materialize bias table [8][784][784] bf16 ----------------
__global__ void bias_pre_kernel(const float* __restrict__ biases,
                                const int* __restrict__ bias_idxs,
                                unsigned short* __restrict__ bias_tab) {
  int t = blockIdx.x * 256 + threadIdx.x;
  if (t >= NN) return;
  int idx = bias_idxs[t];
  for (int h = 0; h < NH; ++h)
    bias_tab[(size_t)h * NN + t] = f2bf(biases[h * Nseq + idx]);
}

// ---------------- K1: QKV GEMM (dbuf glds pipeline) + BN + LDS-staged scatter ----------------
__global__ __launch_bounds__(256, 2) void qkv_gemm_kernel(
    const unsigned short* __restrict__ A,
    const unsigned short* __restrict__ Bw,
    const float* __restrict__ gamma, const float* __restrict__ beta,
    const float* __restrict__ mean,  const float* __restrict__ var,
    unsigned short* __restrict__ qo,   // [B,H,N,64] (pre-scaled by 0.125)
    unsigned short* __restrict__ ko,   // [B,H,N,64]
    unsigned short* __restrict__ vto)  // [B,H,256,N]
{
  const int K = DIM;
  __shared__ unsigned short smem[128 * OSTR];
  int tid = threadIdx.x;
  int wave = tid >> 6, lane = tid & 63;
  int quad = lane >> 4, l16 = lane & 15;
  int wm = wave >> 1, wn = wave & 1;
  int m0 = blockIdx.y * 128, n0 = blockIdx.x * 128;

  int srow = wave * 32 + (lane >> 2);
  int sch = (lane & 3) * 8;
  const unsigned short* Ab = A + (size_t)(m0 + srow) * K + sch;
  const unsigned short* Bb = Bw + (size_t)(n0 + srow) * K + sch;
  unsigned short* AsW = &smem[wave * 1024];
  unsigned short* BsW = &smem[4096 + wave * 1024];

  floatx4 acc[4][4];
  for (int i = 0; i < 4; ++i)
    for (int j = 0; j < 4; ++j) acc[i][j] = (floatx4)0.0f;

  glds16(Ab, AsW);
  glds16(Ab + 16 * K, AsW + 512);
  glds16(Bb, BsW);
  glds16(Bb + 16 * K, BsW + 512);

  for (int k = 0; k < 16; ++k) {
    int cur = k & 1, nb = cur ^ 1;
    __builtin_amdgcn_s_waitcnt(0xC07F);
    __builtin_amdgcn_s_barrier();
    int k0n = ((k + 1) & 15) * 32;
    glds16(Ab + k0n, AsW + nb * 8192);
    glds16(Ab + k0n + 16 * K, AsW + nb * 8192 + 512);
    glds16(Bb + k0n, BsW + nb * 8192);
    glds16(Bb + k0n + 16 * K, BsW + nb * 8192 + 512);
    __builtin_amdgcn_s_waitcnt(0x0F74);   // vmcnt(4)
    __builtin_amdgcn_s_barrier();

    const unsigned short* As = &smem[cur * 8192];
    const unsigned short* Bs = &smem[4096 + cur * 8192];
    short8 af[4], bfr[4];
    for (int mt = 0; mt < 4; ++mt)
      af[mt] = *(const short8*)&As[(wm * 64 + mt * 16 + l16) * 32 + quad * 8];
    for (int nt = 0; nt < 4; ++nt)
      bfr[nt] = *(const short8*)&Bs[(wn * 64 + nt * 16 + l16) * 32 + quad * 8];
    for (int mt = 0; mt < 4; ++mt)
      for (int nt = 0; nt < 4; ++nt)
        acc[mt][nt] = __builtin_amdgcn_mfma_f32_16x16x32_bf16(af[mt], bfr[nt], acc[mt][nt], 0, 0, 0);
  }

  int tt = n0 % 384;        // 0 => QK tile; 128/256 => V tile
  int h = n0 / 384;
  __builtin_amdgcn_s_waitcnt(0x0070);
  __syncthreads();

  if (tt == 0) {
    for (int nt = 0; nt < 4; ++nt) {
      int o = n0 + wn * 64 + nt * 16 + l16;
      float sc = gamma[o] * rsqrtf(var[o] + 1e-5f);
      float bb = beta[o] - mean[o] * sc;
      if (wn == 0) { sc *= 0.125f; bb *= 0.125f; }
      int jl = wn * 64 + nt * 16 + l16;
      for (int mt = 0; mt < 4; ++mt)
        for (int r = 0; r < 4; ++r) {
          int ml = wm * 64 + mt * 16 + quad * 4 + r;
          smem[ml * OSTR + jl] = f2bf(acc[mt][nt][r] * sc + bb);
        }
    }
    __syncthreads();
    for (int i = 0; i < 8; ++i) {
      int c = i * 256 + tid;
      int ml = c >> 4, jc = c & 15;
      int m = m0 + ml;
      int b = m / 784, n = m - b * 784;
      uint4 v = *(uint4*)&smem[ml * OSTR + jc * 8];
      int j = jc * 8;
      if (j < 64) *(uint4*)&qo[(((size_t)b * NH + h) * Nseq + n) * KD + j] = v;
      else        *(uint4*)&ko[(((size_t)b * NH + h) * Nseq + n) * KD + (j - 64)] = v;
    }
  } else {
    for (int nt = 0; nt < 4; ++nt) {
      int o = n0 + wn * 64 + nt * 16 + l16;
      float sc = gamma[o] * rsqrtf(var[o] + 1e-5f);
      float bb = beta[o] - mean[o] * sc;
      int cl = wn * 64 + nt * 16 + l16;
      for (int mt = 0; mt < 4; ++mt)
        for (int r = 0; r < 4; ++r) {
          int ml = wm * 64 + mt * 16 + quad * 4 + r;
          smem[cl * OSTR + ml] = f2bf(acc[mt][nt][r] * sc + bb);
        }
    }
    __syncthreads();
    int cbase = tt - 128;
    for (int i = 0; i < 8; ++i) {
      int c = i * 256 + tid;
      int cl = c >> 4, mc = c & 15;
      int m = m0 + mc * 8;
      int b = m / 784, n = m - b * 784;
      uint4 v = *(uint4*)&smem[cl * OSTR + mc * 8];
      *(uint4*)&vto[(((size_t)b * NH + h) * VD + cbase + cl) * Nseq + n] = v;
    }
  }
}

// ---------------- K2: flash attention, 32x32 MFMA, LDS-BW-optimized ----------------
// 8 waves. QK: wave (jt=w>>2, it=w&3) computes one 32j x 32i S^T tile with
// mfma_32x32x16 (4 kf b128 reads). P strip [128 rows][64 j] is block-shared
// (extra lgkm-only barrier). PV: wave (rg=w>>2, cg=w&3) computes 64 rows x 64 ch
// as 2x2 of 32x32 (8 pf + 8 vf b128 reads). Per-CU LDS reads/kt: 160 b128
// (was 336 with 16x16) — attacks the measured LDS-BW bound.
// C/D layout (verified, guide m74/m101): col=lane&31, row=(reg&3)+8*(reg>>2)+4*(lane>>5).
__global__ __launch_bounds__(512, 2) void attn_kernel(
    const unsigned short* __restrict__ qb,   // [bh][784][64] (pre-scaled by 1/8)
    const unsigned short* __restrict__ kb,   // [bh][784][64]
    const unsigned short* __restrict__ vtb,  // [bh][256][784]
    const unsigned short* __restrict__ bias_tab, // [8][784][784] bf16
    unsigned short* __restrict__ U)          // [16*784*2048] bf16 (post-SiLU)
{
  __shared__ unsigned short smem[65536];        // 128 KB carve
  unsigned short* vt_lds = smem;                // 2 x 256x64 (64 KB), dbuf, swizzled
  unsigned short* k_lds  = smem + 32768;        // 2 x 64x64 (16 KB), dbuf, swizzled
  unsigned short* bs_lds = smem + 40960;        // 2 x 128x64 (32 KB), dbuf, swizzled
  unsigned short* ps_lds = smem + 57344;        // 128x64 (16 KB), swizzled, block-shared
  float* lsum_lds = (float*)(smem + 32768);     // aliases k_lds (dead at epilogue)

  int tid = threadIdx.x;
  int wave = tid >> 6, lane = tid & 63;
  int l5 = lane >> 5;        // half-wave
  int i32 = lane & 31;
  int l7 = lane & 7;

  int L = blockIdx.x;
  int xcd = L & 7;
  int s = L >> 3;            // 0..111
  int qp = s % 7;            // 128-row Q group
  int bg = s / 7;            // batch
  int bh = bg * 8 + xcd;     // bh % 8 == h == xcd (head-bias L2 locality)
  int b = bg, h = xcd;

  int jt = wave >> 2;        // QK j-tile (32 j)
  int it = wave & 3;         // QK i-tile (32 i)
  int rg = wave >> 2;        // PV row group (64 rows)
  int cg = wave & 3;         // PV ch group (64 ch)
  int iRow = it * 32 + i32;  // this lane's S^T column (block-local Q row)

  const unsigned short* brow = bias_tab + (size_t)h * NN;

  // glds staging lane mapping (phys 16B chunk = logical ^ (row&7))
  int lc = lane >> 3;
  int lch = (lane & 7) ^ lc;

  const unsigned short* vsrc[4];
#pragma unroll
  for (int t = 0; t < 4; ++t)
    vsrc[t] = vtb + ((size_t)bh * VD + t * 64 + wave * 8 + lc) * Nseq + lch * 8;
  const unsigned short* ksrc =
      kb + (size_t)bh * (Nseq * KD) + (wave * 8 + lc) * KD + lch * 8;
  const unsigned short* bsrc[2];
#pragma unroll
  for (int t = 0; t < 2; ++t) {
    int ig = qp * 128 + t * 64 + wave * 8 + lc;
    if (ig > Nseq - 1) ig = Nseq - 1;   // clamp dead rows
    bsrc[t] = brow + (size_t)ig * Nseq + lch * 8;
  }

  // ---- prologue: issue tile 0 (7 glds/lane) ----
#pragma unroll
  for (int t = 0; t < 4; ++t)
    glds16(vsrc[t], &vt_lds[(t * 64 + wave * 8) * 64]);
  glds16(ksrc, &k_lds[wave * 512]);
#pragma unroll
  for (int t = 0; t < 2; ++t)
    glds16(bsrc[t], &bs_lds[(t * 64 + wave * 8) * 64]);

  // Q B-fragments for 32x32x16: B[k=d][n=i]: lane n=i32, k=l5*8+e; 4 k-steps
  short8 qf[4];
  {
    const unsigned short* qpp = qb + ((size_t)bh * Nseq + qp * 128 + iRow) * KD;
#pragma unroll
    for (int ks = 0; ks < 4; ++ks)
      qf[ks] = *(const short8*)(qpp + ks * 16 + l5 * 8);
  }

  float lsum = 0.0f;
  floatx16 oacc[2][2];
#pragma unroll
  for (int rt = 0; rt < 2; ++rt)
#pragma unroll
    for (int ct = 0; ct < 2; ++ct) oacc[rt][ct] = (floatx16)0.0f;

  for (int kt = 0; kt < 13; ++kt) {
    int cur = kt & 1;
    int nb = cur ^ 1;
    // barrier A: all waves done with staging buf nb (compute of kt-1 finished)
    __builtin_amdgcn_s_waitcnt(0xC07F);   // lgkmcnt(0) only
    __builtin_amdgcn_s_barrier();

    int ktn = kt + 1; if (ktn >= 13) ktn = 0;   // wrap keeps vmcnt uniform
#pragma unroll
    for (int t = 0; t < 4; ++t)
      glds16(vsrc[t] + ktn * 64, &vt_lds[nb * 16384 + (t * 64 + wave * 8) * 64]);
    glds16(ksrc + (size_t)ktn * 4096, &k_lds[nb * 4096 + wave * 512]);
#pragma unroll
    for (int t = 0; t < 2; ++t)
      glds16(bsrc[t] + ktn * 64, &bs_lds[nb * 8192 + (t * 64 + wave * 8) * 64]);

    // barrier B: tile kt landed (7 of kt+1 stay in flight)
    __builtin_amdgcn_s_waitcnt(0x0F77);   // vmcnt(7)
    __builtin_amdgcn_s_barrier();

    const unsigned short* kbuf = &k_lds[cur * 4096];
    const unsigned short* vbuf = &vt_lds[cur * 16384];
    const unsigned short* bbuf = &bs_lds[cur * 8192];

    // S^T tile (32j x 32i) = K Q^T via 32x32x16; A=K: lane m=j=i32, k=l5*8+e
    floatx16 st = (floatx16)0.0f;
#pragma unroll
    for (int ks = 0; ks < 4; ++ks) {
      short8 kf = *(const short8*)&kbuf[(jt * 32 + i32) * 64 + (((ks << 1) + l5) ^ l7) * 8];
      st = __builtin_amdgcn_mfma_f32_32x32x16_bf16(kf, qf[ks], st, 0, 0, 0);
    }

    // bias + no-max softmax + packed P write. Reg-quad q holds 4 consecutive j:
    // j_in_tile = 8q + 4*l5 + e  ->  16B chunk (jt*4+q), offset 4*l5.
    bool tail = (kt == 12);
#pragma unroll
    for (int q = 0; q < 4; ++q) {
      int chunk = ((jt << 2) + q) ^ l7;
      int off = iRow * 64 + chunk * 8 + l5 * 4;
      ushort4 bv = *(const ushort4*)&bbuf[off];
      float p0 = EXP2((st[q * 4 + 0] + bf2f(bv.x)) * LOG2E);
      float p1 = EXP2((st[q * 4 + 1] + bf2f(bv.y)) * LOG2E);
      float p2 = EXP2((st[q * 4 + 2] + bf2f(bv.z)) * LOG2E);
      float p3 = EXP2((st[q * 4 + 3] + bf2f(bv.w)) * LOG2E);
      if (tail && (jt == 1 || q >= 2)) { p0 = 0.0f; p1 = 0.0f; p2 = 0.0f; p3 = 0.0f; }
      lsum += (p0 + p1) + (p2 + p3);
      unsigned lo = (unsigned)f2bf(p0) | ((unsigned)f2bf(p1) << 16);
      unsigned hi = (unsigned)f2bf(p2) | ((unsigned)f2bf(p3) << 16);
      *(uint2*)&ps_lds[off] = make_uint2(lo, hi);
    }

    // barrier C: P strip is block-shared (PV reads cross wave strips)
    __builtin_amdgcn_s_waitcnt(0xC07F);   // lgkmcnt(0) only
    __builtin_amdgcn_s_barrier();

    // PV: 2x2 of 32x32 tiles (64 rows x 64 ch per wave)
#pragma unroll
    for (int ks = 0; ks < 4; ++ks) {
      int pch = (((ks << 1) + l5) ^ l7) * 8;
      short8 a0 = *(const short8*)&ps_lds[(rg * 64 + i32) * 64 + pch];
      short8 a1 = *(const short8*)&ps_lds[(rg * 64 + 32 + i32) * 64 + pch];
      short8 b0 = *(const short8*)&vbuf[(cg * 64 + i32) * 64 + pch];
      short8 b1 = *(const short8*)&vbuf[(cg * 64 + 32 + i32) * 64 + pch];
      oacc[0][0] = __builtin_amdgcn_mfma_f32_32x32x16_bf16(a0, b0, oacc[0][0], 0, 0, 0);
      oacc[0][1] = __builtin_amdgcn_mfma_f32_32x32x16_bf16(a0, b1, oacc[0][1], 0, 0, 0);
      oacc[1][0] = __builtin_amdgcn_mfma_f32_32x32x16_bf16(a1, b0, oacc[1][0], 0, 0, 0);
      oacc[1][1] = __builtin_amdgcn_mfma_f32_32x32x16_bf16(a1, b1, oacc[1][1], 0, 0, 0);
    }
  }

  // drain remaining async glds, then reduce lsum (per-column partials)
  __builtin_amdgcn_s_waitcnt(0x0070);   // vmcnt(0) + lgkmcnt(0)
  lsum += __shfl_xor(lsum, 32);
  if (lane < 32) lsum_lds[jt * 128 + iRow] = lsum;
  __syncthreads();
  if (tid < 128) {
    float tot = lsum_lds[tid] + lsum_lds[128 + tid];
    lsum_lds[tid] = 1.0f / tot;
  }
  __syncthreads();

  // epilogue: normalize, SiLU, write U (rows rg*64.., ch cg*64..)
#pragma unroll
  for (int rt = 0; rt < 2; ++rt) {
#pragma unroll
    for (int e = 0; e < 16; ++e) {
      int row = rg * 64 + rt * 32 + (e & 3) + 8 * (e >> 2) + 4 * l5;
      int ig = qp * 128 + row;
      if (ig < Nseq) {
        float iv = lsum_lds[row];
        size_t base = ((size_t)b * Nseq + ig) * HV + h * VD + cg * 64;
        float u0 = oacc[rt][0][e] * iv;
        float u1 = oacc[rt][1][e] * iv;
        float s0 = 1.0f / (1.0f + EXP2(-u0 * LOG2E));
        float s1 = 1.0f / (1.0f + EXP2(-u1 * LOG2E));
        U[base + i32]      = f2bf(u0 * s0);
        U[base + 32 + i32] = f2bf(u1 * s1);
      }
    }
  }
}

// ---------------- K3: proj GEMM (dbuf glds pipeline, operand-swapped) + BN ----------------
__global__ __launch_bounds__(256, 2) void proj_gemm_kernel(
    const unsigned short* __restrict__ Ubuf,  // [12544][2048]
    const unsigned short* __restrict__ Wp,    // [512][2048]
    const float* __restrict__ gamma, const float* __restrict__ beta,
    const float* __restrict__ mean,  const float* __restrict__ var,
    float* __restrict__ out)                  // [12544][512]
{
  const int K = HV;
  __shared__ unsigned short smem[16384];
  int tid = threadIdx.x;
  int wave = tid >> 6, lane = tid & 63;
  int quad = lane >> 4, l16 = lane & 15;
  int wm = wave >> 1, wn = wave & 1;
  int o0 = blockIdx.y * 128, mB = blockIdx.x * 128;

  int srow = wave * 32 + (lane >> 2);
  int sch = (lane & 3) * 8;
  const unsigned short* Ab = Wp + (size_t)(o0 + srow) * K + sch;
  const unsigned short* Bb = Ubuf + (size_t)(mB + srow) * K + sch;
  unsigned short* AsW = &smem[wave * 1024];
  unsigned short* BsW = &smem[4096 + wave * 1024];

  floatx4 acc[4][4];
  for (int i = 0; i < 4; ++i)
    for (int j = 0; j < 4; ++j) acc[i][j] = (floatx4)0.0f;

  glds16(Ab, AsW);
  glds16(Ab + 16 * K, AsW + 512);
  glds16(Bb, BsW);
  glds16(Bb + 16 * K, BsW + 512);

  for (int k = 0; k < 64; ++k) {
    int cur = k & 1, nb = cur ^ 1;
    __builtin_amdgcn_s_waitcnt(0xC07F);
    __builtin_amdgcn_s_barrier();
    int k0n = ((k + 1) & 63) * 32;
    glds16(Ab + k0n, AsW + nb * 8192);
    glds16(Ab + k0n + 16 * K, AsW + nb * 8192 + 512);
    glds16(Bb + k0n, BsW + nb * 8192);
    glds16(Bb + k0n + 16 * K, BsW + nb * 8192 + 512);
    __builtin_amdgcn_s_waitcnt(0x0F74);   // vmcnt(4)
    __builtin_amdgcn_s_barrier();

    const unsigned short* As = &smem[cur * 8192];
    const unsigned short* Bs = &smem[4096 + cur * 8192];
    short8 af[4], bfr[4];
    for (int mt = 0; mt < 4; ++mt)
      af[mt] = *(const short8*)&As[(wm * 64 + mt * 16 + l16) * 32 + quad * 8];
    for (int nt = 0; nt < 4; ++nt)
      bfr[nt] = *(const short8*)&Bs[(wn * 64 + nt * 16 + l16) * 32 + quad * 8];
    for (int mt = 0; mt < 4; ++mt)
      for (int nt = 0; nt < 4; ++nt)
        acc[mt][nt] = __builtin_amdgcn_mfma_f32_16x16x32_bf16(af[mt], bfr[nt], acc[mt][nt], 0, 0, 0);
  }
  __builtin_amdgcn_s_waitcnt(0x0070);

  for (int mt = 0; mt < 4; ++mt) {
    int ob = o0 + wm * 64 + mt * 16 + quad * 4;
    float4 g = *(const float4*)&gamma[ob];
    float4 vr = *(const float4*)&var[ob];
    float4 mn = *(const float4*)&mean[ob];
    float4 bt = *(const float4*)&beta[ob];
    float sc0 = g.x * rsqrtf(vr.x + 1e-5f), bb0 = bt.x - mn.x * sc0;
    float sc1 = g.y * rsqrtf(vr.y + 1e-5f), bb1 = bt.y - mn.y * sc1;
    float sc2 = g.z * rsqrtf(vr.z + 1e-5f), bb2 = bt.z - mn.z * sc2;
    float sc3 = g.w * rsqrtf(vr.w + 1e-5f), bb3 = bt.w - mn.w * sc3;
    for (int nt = 0; nt < 4; ++nt) {
      int m = mB + wn * 64 + nt * 16 + l16;
      float4 v;
      v.x = acc[mt][nt][0] * sc0 + bb0;
      v.y = acc[mt][nt][1] * sc1 + bb1;
      v.z = acc[mt][nt][2] * sc2 + bb2;
      v.w = acc[mt][nt][3] * sc3 + bb3;
      *(float4*)&out[(size_t)m * DIM + ob] = v;
    }
  }
}

// ---------------- launch ----------------
extern "C" void kernel_launch(void* const* d_in, const int* in_sizes, int n_in,
                              void* d_out, int out_size, void* d_ws, size_t ws_size,
                              hipStream_t stream) {
  const float* x          = (const float*)d_in[0];
  const float* qkv_w      = (const float*)d_in[1];
  const float* qkv_gamma  = (const float*)d_in[2];
  const float* qkv_beta   = (const float*)d_in[3];
  const float* qkv_mean   = (const float*)d_in[4];
  const float* qkv_var    = (const float*)d_in[5];
  const float* att_biases = (const float*)d_in[6];
  const float* proj_w     = (const float*)d_in[7];
  const float* proj_gamma = (const float*)d_in[8];
  const float* proj_beta  = (const float*)d_in[9];
  const float* proj_mean  = (const float*)d_in[10];
  const float* proj_var   = (const float*)d_in[11];
  const int*   bias_idxs  = (const int*)d_in[12];
  float* out = (float*)d_out;

  char* ws = (char*)d_ws;
  unsigned short* xb  = (unsigned short*)(ws);                 // 12544*512 (12.85 MB)
  unsigned short* bias_tab = (unsigned short*)(ws);            // 8*784*784 bf16 — aliases xb (dead after qkv_gemm)
  unsigned short* wq  = (unsigned short*)(ws + 12845056);      // 3072*512
  unsigned short* wp  = (unsigned short*)(ws + 15990784);      // 512*2048
  unsigned short* qo  = (unsigned short*)(ws + 18087936);      // 16*8*784*64
  unsigned short* ko  = (unsigned short*)(ws + 30932992);      // 16*8*784*64
  unsigned short* vto = (unsigned short*)(ws + 43778048);      // 16*8*256*784
  unsigned short* Ub  = (unsigned short*)(ws + 95158272);      // 12544*2048
  // total: 146538496 bytes

  {
    int n4 = N4X + N4Q + N4P;
    cvt_all_kernel<<<(n4 + 255) / 256, 256, 0, stream>>>(x, qkv_w, proj_w, xb, wq, wp);
  }

  qkv_gemm_kernel<<<dim3(QKV_OUT / 128, (Bsz * Nseq) / 128), 256, 0, stream>>>(
      xb, wq, qkv_gamma, qkv_beta, qkv_mean, qkv_var, qo, ko, vto);

  bias_pre_kernel<<<(NN + 255) / 256, 256, 0, stream>>>(att_biases, bias_idxs, bias_tab);

  attn_kernel<<<7 * Bsz * NH, 512, 0, stream>>>(qo, ko, vto, bias_tab, Ub);

  proj_gemm_kernel<<<dim3((Bsz * Nseq) / 128, DIM / 128), 256, 0, stream>>>(
      Ub, wp, proj_gamma, proj_beta, proj_mean, proj_var, out);
}